// Round 10
// baseline (576.786 us; speedup 1.0000x reference)
//
#include <hip/hip_runtime.h>
#include <hip/hip_bf16.h>

// Problem constants (fixed by reference)
#define NN 100000
#define EE 1600000
#define HH 128
#define NB 391      // buckets = ceil(NN/256)
#define CAP 5120    // padded bucket capacity
#define GB 1563     // gemm tiles = ceil(NN/64)
#define SB 256      // scatter blocks
#define EPB (EE / SB)   // 6250 edges per scatter block (exact)
#define PPB 512     // prep blocks (131072 weight elems / 256)
#define FB 6250     // final blocks: 16 nodes/block (4 waves x 4 nodes)
#define AB 6250     // aggregate blocks: 16 nodes/block

typedef short bf16x8 __attribute__((ext_vector_type(8)));
typedef short bf16x4 __attribute__((ext_vector_type(4)));
typedef float f32x4  __attribute__((ext_vector_type(4)));

__device__ inline short f2bf(float v) {
    __hip_bfloat16 b = __float2bfloat16(v);
    return *reinterpret_cast<short*>(&b);
}
__device__ inline float bf2f(short s) {
    unsigned int u = ((unsigned int)(unsigned short)s) << 16;
    return *reinterpret_cast<float*>(&u);
}

// direct global->LDS staging (16B per lane, LDS dest = uniform base + lane*16)
typedef __attribute__((address_space(1))) void gvoid_t;
typedef __attribute__((address_space(3))) void svoid_t;
__device__ __forceinline__ void gload16(const void* g, void* l) {
    __builtin_amdgcn_global_load_lds((gvoid_t*)g, (svoid_t*)l, 16, 0, 0);
}

// Compiler-order fence (r2 lesson: asm waitcnt orders the HW, not the compiler)
__device__ __forceinline__ void ld_fence() { asm volatile("" ::: "memory"); }

// counted-vmcnt barrier: wait own outstanding vmem down to N, then raw s_barrier.
template <int N>
__device__ __forceinline__ void wait_vm_bar() {
    if constexpr (N == 0)
        asm volatile("s_waitcnt vmcnt(0)\n\ts_barrier" ::: "memory");
    else if constexpr (N == 4)
        asm volatile("s_waitcnt vmcnt(4)\n\ts_barrier" ::: "memory");
    else if constexpr (N == 12)
        asm volatile("s_waitcnt vmcnt(12)\n\ts_barrier" ::: "memory");
    else if constexpr (N == 16)
        asm volatile("s_waitcnt vmcnt(16)\n\ts_barrier" ::: "memory");
    else if constexpr (N == 18)
        asm volatile("s_waitcnt vmcnt(18)\n\ts_barrier" ::: "memory");
    else
        static_assert(N == 0 || N == 4 || N == 12 || N == 16 || N == 18, "bad N");
}
__device__ __forceinline__ void barrier_only() {
    asm volatile("s_barrier" ::: "memory");
}

// ---------------------------------------------------------------------------
// Launch 1 (r10): edge scatter (blocks [0,SB)) FUSED with weight prep
// (blocks [SB, SB+PPB)). Independent work — bcur zeroing moved to
// hipMemsetAsync so scatter can't race it. Removes prep's exposed time.
// Scatter: SB x 6250 edges, 16-deep register-blocked loads both passes.
// ---------------------------------------------------------------------------
__global__ __launch_bounds__(256) void prep_scatter_kernel(
    const float* __restrict__ Wl0, const float* __restrict__ Wr0,
    const float* __restrict__ Wl1, const float* __restrict__ Wr1,
    const float* __restrict__ Wl2, const float* __restrict__ Wr2,
    __hip_bfloat16* __restrict__ WT0, __hip_bfloat16* __restrict__ WT1,
    __hip_bfloat16* __restrict__ WT2,
    const int* __restrict__ srcv, const int* __restrict__ dstv,
    int* __restrict__ bcur, int* __restrict__ pairs) {
    __shared__ int hist[NB];
    __shared__ int base[NB];
    const int t = threadIdx.x;

    if (blockIdx.x >= SB) {                      // weight prep
        int id = (blockIdx.x - SB) * 256 + t;    // 0 .. 131071
        if (id < 65536) {                        // layer 0: K=256
            int k = id & 255, n = id >> 8;
            float v = (n < 128) ? Wl0[(size_t)k * 128 + n]
                                : Wr0[(size_t)k * 128 + (n - 128)];
            WT0[(size_t)n * 256 + k] = __float2bfloat16(v);
        } else {
            id -= 65536;
            int layer = id >> 15;                // 0 -> L1, 1 -> L2
            int u = id & 32767;
            int k = u & 127, n = u >> 7;
            const float* Wl = layer ? Wl2 : Wl1;
            const float* Wr = layer ? Wr2 : Wr1;
            __hip_bfloat16* WT = layer ? WT2 : WT1;
            float v = (n < 128) ? Wl[(size_t)k * 128 + n]
                                : Wr[(size_t)k * 128 + (n - 128)];
            WT[(size_t)n * 128 + k] = __float2bfloat16(v);
        }
        return;
    }

    for (int j = t; j < NB; j += 256) hist[j] = 0;
    __syncthreads();

    const int e0    = blockIdx.x * EPB;
    const int eend_ = e0 + EPB;

    for (int be = e0; be < eend_; be += 4096) {
        int d[16];
#pragma unroll
        for (int u = 0; u < 16; ++u) {
            const int e = be + u * 256 + t;
            d[u] = (e < eend_) ? dstv[e] : -1;
        }
#pragma unroll
        for (int u = 0; u < 16; ++u)
            if (d[u] >= 0) atomicAdd(&hist[d[u] >> 8], 1);
    }
    __syncthreads();

    for (int j = t; j < NB; j += 256)
        base[j] = hist[j] ? atomicAdd(&bcur[j], hist[j]) : 0;
    __syncthreads();
    for (int j = t; j < NB; j += 256) hist[j] = base[j];   // reuse as cursor
    __syncthreads();

    for (int be = e0; be < eend_; be += 4096) {
        int s[16], d[16];
#pragma unroll
        for (int u = 0; u < 16; ++u) {
            const int e = be + u * 256 + t;
            if (e < eend_) { s[u] = srcv[e]; d[u] = dstv[e]; }
            else d[u] = -1;
        }
#pragma unroll
        for (int u = 0; u < 16; ++u)
            if (d[u] >= 0) {
                const int b   = d[u] >> 8;
                const int pos = atomicAdd(&hist[b], 1);
                if (pos < CAP) pairs[b * CAP + pos] = (s[u] << 8) | (d[u] & 255);
            }
    }
}

// ---------------------------------------------------------------------------
// MFMA GEMM body, r10: [z|r] = h @ [Wl|Wr], 64-row tile, 4 waves.
// L0 now DBUF (2x16KB stage, epilogue aliased) -> LDS 33.8KB -> 4 blocks/CU
// (was 3 at 48KB). Rationale: 5 intra-block schedules all landed 64-80us;
// the untried axis is inter-block TLP covering the L3-hit staging latency.
// Cost: stage(s+2) now issued after compute(s) (1-phase lookahead vs 2).
// Fenced issue order + waits (L0): W0 W1 S0 S1 | w4 C0 bar {S2 W2} |
// w12 C1 bar {S3 W3} | w12 C2 bar | w0 C3 bar | epi.
// Hidden branch unchanged (r18). VGPR stays ~92 (2-deep wreg).
// ---------------------------------------------------------------------------
#define EW 264    // epilogue LDS row stride in halves (528 B, 16B-aligned)
template <int K, bool FIRST>
__device__ __forceinline__ void gemm_body(
    short* __restrict__ lsh, int bid,
    const __hip_bfloat16* hin,
    const float* __restrict__ x0, const float* __restrict__ x1,
    const float* __restrict__ x2, const float* __restrict__ x3,
    const __hip_bfloat16* __restrict__ wt, const float* __restrict__ bias,
    __hip_bfloat16* zout, __hip_bfloat16* __restrict__ rout) {
    const int t    = threadIdx.x;
    const int w    = t >> 6;
    const int lane = t & 63;
    const int quad = lane >> 4;
    const int l16  = lane & 15;
    const int n0   = bid * 64;

    constexpr int BUFB = FIRST ? 16384 : 8192;   // LDS bytes per stage buffer
    char* const lc = (char*)lsh;

    const __hip_bfloat16* afeat[4];
#pragma unroll
    for (int ft = 0; ft < 4; ++ft)
        afeat[ft] = wt + (size_t)(w * 64 + ft * 16 + l16) * K + quad * 8;

    f32x4 acc[4][4];
#pragma unroll
    for (int ft = 0; ft < 4; ++ft)
#pragma unroll
        for (int nt = 0; nt < 4; ++nt)
            acc[ft][nt] = (f32x4){0.f, 0.f, 0.f, 0.f};

    bf16x8 wreg[2][8];   // [parity][kcl*4+ft]

    auto loadW = [&](int p, int pb) {
#pragma unroll
        for (int kcl = 0; kcl < 2; ++kcl)
#pragma unroll
            for (int ft = 0; ft < 4; ++ft)
                wreg[pb][kcl * 4 + ft] =
                    *(const bf16x8*)(afeat[ft] + (p * 2 + kcl) * 32);
    };

    auto stage = [&](int p, int bb) {
        char* lb = lc + bb * BUFB;
        if constexpr (FIRST) {
            const float* sp = (p == 0) ? x0 : (p == 1) ? x1 : (p == 2) ? x2 : x3;
#pragma unroll
            for (int i = 0; i < 4; ++i) {
                const int j   = w * 4 + i;           // 1KB chunk = 4 rows
                const int row = j * 4 + (lane >> 4);
                int rg = n0 + row; if (rg > NN - 1) rg = NN - 1;
                const int colb = ((lane & 15) * 16) ^ ((row & 15) << 4);
                gload16((const char*)sp + (size_t)rg * 256 + colb, lb + j * 1024);
            }
        } else {
#pragma unroll
            for (int i = 0; i < 2; ++i) {
                const int j   = w * 2 + i;           // 1KB chunk = 8 rows
                const int row = j * 8 + (lane >> 3);
                int rg = n0 + row; if (rg > NN - 1) rg = NN - 1;
                const int colb = ((lane & 7) * 16) ^ ((row & 7) << 4);
                gload16((const char*)hin + (size_t)rg * 256 + p * 128 + colb,
                        lb + j * 1024);
            }
        }
    };

    auto compute = [&](int s, int bb, int pb) {
        const char* lb = lc + bb * BUFB;
#pragma unroll
        for (int kcl = 0; kcl < 2; ++kcl) {
#pragma unroll
            for (int nt = 0; nt < 4; ++nt) {
                const int row = nt * 16 + l16;
                bf16x8 b;
                if constexpr (FIRST) {
                    const int sw = (row & 15) << 4;
                    const int B0 = kcl * 128 + quad * 32;
                    const char* rb = lb + row * 256;
                    const f32x4 lo = *(const f32x4*)(rb + ((B0) ^ sw));
                    const f32x4 hi = *(const f32x4*)(rb + ((B0 + 16) ^ sw));
                    b[0] = f2bf(lo[0]); b[1] = f2bf(lo[1]);
                    b[2] = f2bf(lo[2]); b[3] = f2bf(lo[3]);
                    b[4] = f2bf(hi[0]); b[5] = f2bf(hi[1]);
                    b[6] = f2bf(hi[2]); b[7] = f2bf(hi[3]);
                } else {
                    const int sw = (row & 7) << 4;
                    const int B0 = kcl * 64 + quad * 16;
                    b = *(const bf16x8*)(lb + row * 128 + (B0 ^ sw));
                }
#pragma unroll
                for (int ft = 0; ft < 4; ++ft)
                    acc[ft][nt] = __builtin_amdgcn_mfma_f32_16x16x32_bf16(
                        wreg[pb][kcl * 4 + ft], b, acc[ft][nt], 0, 0, 0);
            }
        }
    };

    if constexpr (FIRST) {                   // NS=4, 2 LDS buffers (dbuf)
        loadW(0, 0); ld_fence();
        loadW(1, 1); ld_fence();
        stage(0, 0); ld_fence();
        stage(1, 1); ld_fence();
        // queue: W0(8) W1(8) S0(4) S1(4) = 24
        wait_vm_bar<4>();                      // retire W0,W1,S0; S1 in flight
        compute(0, 0, 0); barrier_only();
        stage(2, 0); ld_fence(); loadW(2, 0); ld_fence();   // out: S1+S2+W2=16
        wait_vm_bar<12>();                     // retire S1; S2,W2 in flight
        compute(1, 1, 1); barrier_only();
        stage(3, 1); ld_fence(); loadW(3, 1); ld_fence();   // out: S2+W2+S3+W3=24
        wait_vm_bar<12>();                     // retire S2,W2; S3,W3 in flight
        compute(2, 0, 0); barrier_only();
        wait_vm_bar<0>();                      // retire S3,W3
        compute(3, 1, 1); barrier_only();
    } else {                                  // NS=2, 2 LDS buffers
        stage(0, 0); ld_fence();
        stage(1, 1); ld_fence();
        loadW(0, 0); loadW(1, 1);
        wait_vm_bar<18>(); compute(0, 0, 0); barrier_only();
        wait_vm_bar<16>(); compute(1, 1, 1); barrier_only();
    }

    // merged epilogue: all 4 waves transpose into [64][256] (z | r+bias),
    // one sync, one cooperative store pass. Aliases the stage buffers
    // (dead after the final barrier above).
#pragma unroll
    for (int ft = 0; ft < 4; ++ft) {
        const int fb = ft * 16 + quad * 4;
        float4 bv = make_float4(0.f, 0.f, 0.f, 0.f);
        if (w >= 2) bv = *(const float4*)&bias[(w - 2) * 64 + fb];
        const int cbase = (w & 1) * 64 + ((w >= 2) ? 128 : 0);
#pragma unroll
        for (int nt = 0; nt < 4; ++nt) {
            const f32x4 a = acc[ft][nt];
            bf16x4 p;
            p[0] = f2bf(a[0] + bv.x); p[1] = f2bf(a[1] + bv.y);
            p[2] = f2bf(a[2] + bv.z); p[3] = f2bf(a[3] + bv.w);
            *(bf16x4*)&lsh[(nt * 16 + l16) * EW + cbase + fb] = p;
        }
    }
    __syncthreads();
#pragma unroll
    for (int u = 0; u < 8; ++u) {            // 64 rows x 32 bf16x8-chunks
        const int id  = u * 256 + t;
        const int row = id >> 5, ch = (id & 31) * 8;
        const int nd  = n0 + row;
        if (nd < NN) {
            const bf16x8 v = *(const bf16x8*)&lsh[row * EW + ch];
            if (ch < 128) *(bf16x8*)&zout[(size_t)nd * HH + ch] = v;
            else          *(bf16x8*)&rout[(size_t)nd * HH + (ch - 128)] = v;
        }
    }
}

// hidden gemm (layers 1,2): LDS = max(2x8KB dbuf, 64x264x2 epilogue) = 33.8KB
template <int K>
__global__ __launch_bounds__(256) void gemm_kernel(
    const __hip_bfloat16* hin,
    const __hip_bfloat16* __restrict__ wt, const float* __restrict__ bias,
    __hip_bfloat16* zout, __hip_bfloat16* __restrict__ rout) {
    __shared__ short lsh[16896];
    gemm_body<K, false>(lsh, blockIdx.x, hin, nullptr, nullptr, nullptr, nullptr,
                        wt, bias, zout, rout);
}

// ---------------------------------------------------------------------------
// Launch 2: FINALIZE (blocks [0,NB)) fused with GEMM L0 (blocks [NB, NB+GB)).
// LDS now 33.8KB (dbuf L0) -> 4 blocks/CU for the gemm part (was 3).
// ---------------------------------------------------------------------------
__global__ __launch_bounds__(256) void fin_gemm0_kernel(
    const float* __restrict__ x0, const float* __restrict__ x1,
    const float* __restrict__ x2, const float* __restrict__ x3,
    const __hip_bfloat16* __restrict__ wt, const float* __restrict__ bias,
    __hip_bfloat16* __restrict__ zout, __hip_bfloat16* __restrict__ rout,
    const int* __restrict__ bcur, const int* __restrict__ pairs,
    int* __restrict__ csr, int* __restrict__ beg, int* __restrict__ eend,
    float* __restrict__ inv) {
    __shared__ short lsh[16896];            // gemm: 2x16KB dbuf; finalize 3KB
    const int t = threadIdx.x;

    if (blockIdx.x >= NB) {
        gemm_body<256, true>(lsh, blockIdx.x - NB, nullptr, x0, x1, x2, x3,
                             wt, bias, zout, rout);
        return;
    }

    int* cnt = (int*)lsh;
    int* scn = cnt + 256;
    int* cur = scn + 256;
    const int b = blockIdx.x;
    int m = bcur[b];
    if (m > CAP) m = CAP;

    cnt[t] = 0;
    __syncthreads();
    for (int e = t; e < m; e += 256)
        atomicAdd(&cnt[pairs[b * CAP + e] & 255], 1);
    __syncthreads();

    const int v = cnt[t];
    scn[t] = v;
    __syncthreads();
    for (int st = 1; st < 256; st <<= 1) {
        int tv = (t >= st) ? scn[t - st] : 0;
        __syncthreads();
        scn[t] += tv;
        __syncthreads();
    }
    const int myStart = scn[t] - v;          // exclusive scan
    cur[t] = myStart;
    __syncthreads();

    for (int e = t; e < m; e += 256) {
        const int pk  = pairs[b * CAP + e];
        const int pos = atomicAdd(&cur[pk & 255], 1);
        csr[b * CAP + pos] = pk >> 8;
    }

    const int node = b * 256 + t;
    if (node < NN) {
        beg[node]  = b * CAP + myStart;
        eend[node] = b * CAP + myStart + v;
        inv[node]  = 1.0f / fmaxf((float)v, 1.0f);
    }
}

// ---------------------------------------------------------------------------
// Aggregation + combine, r10: h_out = relu(mean_{in-edges}(z[src]) + r).
// 4 nodes/wave, 16-lane groups, lane-local features (r9). NEW: 8-deep
// edge unroll (was 4) — agg is gather-latency-bound (r8: 194MB L2-miss at
// only 3 TB/s), VGPR was 28 so deepen MLP. Tail: unmasked 4 + masked 4.
// ---------------------------------------------------------------------------
template <bool LAST>
__global__ __launch_bounds__(256) void aggregate_kernel(
    const __hip_bfloat16* __restrict__ z, __hip_bfloat16* __restrict__ rio,
    const int* __restrict__ beg, const int* __restrict__ eend,
    const int* __restrict__ csr, const float* __restrict__ inv,
    const float* __restrict__ Wl3, const float* __restrict__ Wr3,
    const float* __restrict__ b3, float* __restrict__ z3,
    float* __restrict__ r3) {
    const int lane = threadIdx.x & 63;
    const int g    = lane >> 4;          // node sub-slot 0..3
    const int l16  = lane & 15;          // feature chunk within the row
    const int i    = ((blockIdx.x * 256 + threadIdx.x) >> 6) * 4 + g;
    if (i >= NN) return;
    const int b0 = beg[i], e0 = eend[i];
    const float iv = inv[i];
    const int  f   = l16 * 8;

    const bf16x8 rv8 = *(const bf16x8*)&rio[(size_t)i * HH + f];

    float acc[8];
#pragma unroll
    for (int j = 0; j < 8; ++j) acc[j] = 0.f;

    const size_t zoff = (size_t)f;
    int e = b0;
    for (; e + 7 < e0; e += 8) {
        int s[8];
#pragma unroll
        for (int u = 0; u < 8; ++u) s[u] = csr[e + u];
        bf16x8 zv[8];
#pragma unroll
        for (int u = 0; u < 8; ++u)
            zv[u] = *(const bf16x8*)&z[(size_t)s[u] * HH + zoff];
#pragma unroll
        for (int j = 0; j < 8; ++j) {
            float a0 = bf2f(zv[0][j]) + bf2f(zv[1][j]);
            float a1 = bf2f(zv[2][j]) + bf2f(zv[3][j]);
            float a2 = bf2f(zv[4][j]) + bf2f(zv[5][j]);
            float a3 = bf2f(zv[6][j]) + bf2f(zv[7][j]);
            acc[j] += (a0 + a1) + (a2 + a3);
        }
    }
    if (e + 3 < e0) {                    // unmasked 4-batch
        const int s0 = csr[e], s1 = csr[e + 1], s2 = csr[e + 2], s3 = csr[e + 3];
        const bf16x8 z0 = *(const bf16x8*)&z[(size_t)s0 * HH + zoff];
        const bf16x8 z1 = *(const bf16x8*)&z[(size_t)s1 * HH + zoff];
        const bf16x8 z2 = *(const bf16x8*)&z[(size_t)s2 * HH + zoff];
        const bf16x8 z3v = *(const bf16x8*)&z[(size_t)s3 * HH + zoff];
#pragma unroll
        for (int j = 0; j < 8; ++j)
            acc[j] += (bf2f(z0[j]) + bf2f(z1[j])) + (bf2f(z2[j]) + bf2f(z3v[j]));
        e += 4;
    }
    if (e < e0) {                        // masked tail (1..3 edges)
        const int s0 = csr[e];
        const int s1 = (e + 1 < e0) ? csr[e + 1] : s0;
        const int s2 = (e + 2 < e0) ? csr[e + 2] : s0;
        const float m1 = (e + 1 < e0) ? 1.f : 0.f;
        const float m2 = (e + 2 < e0) ? 1.f : 0.f;
        const bf16x8 z0 = *(const bf16x8*)&z[(size_t)s0 * HH + zoff];
        const bf16x8 z1 = *(const bf16x8*)&z[(size_t)s1 * HH + zoff];
        const bf16x8 z2 = *(const bf16x8*)&z[(size_t)s2 * HH + zoff];
#pragma unroll
        for (int j = 0; j < 8; ++j) {
            acc[j] += bf2f(z0[j]);
            acc[j] = fmaf(m1, bf2f(z1[j]), acc[j]);
            acc[j] = fmaf(m2, bf2f(z2[j]), acc[j]);
        }
    }

    float ox[8];
    const __hip_bfloat162* rp = (const __hip_bfloat162*)&rv8;
#pragma unroll
    for (int j = 0; j < 4; ++j) {
        ox[2 * j]     = fmaxf(acc[2 * j]     * iv + __bfloat162float(rp[j].x), 0.f);
        ox[2 * j + 1] = fmaxf(acc[2 * j + 1] * iv + __bfloat162float(rp[j].y), 0.f);
    }

    if (!LAST) {
        bf16x8 o;
#pragma unroll
        for (int j = 0; j < 8; ++j) o[j] = f2bf(ox[j]);
        *(bf16x8*)&rio[(size_t)i * HH + f] = o;
    } else {
        const float4 wl0 = *(const float4*)&Wl3[f];
        const float4 wl1 = *(const float4*)&Wl3[f + 4];
        const float4 wr0 = *(const float4*)&Wr3[f];
        const float4 wr1 = *(const float4*)&Wr3[f + 4];
        float al = ox[0] * wl0.x + ox[1] * wl0.y + ox[2] * wl0.z + ox[3] * wl0.w
                 + ox[4] * wl1.x + ox[5] * wl1.y + ox[6] * wl1.z + ox[7] * wl1.w;
        float ar = ox[0] * wr0.x + ox[1] * wr0.y + ox[2] * wr0.z + ox[3] * wr0.w
                 + ox[4] * wr1.x + ox[5] * wr1.y + ox[6] * wr1.z + ox[7] * wr1.w;
#pragma unroll
        for (int m = 8; m; m >>= 1) {     // reduce within the 16-lane group
            al += __shfl_xor(al, m, 64);
            ar += __shfl_xor(ar, m, 64);
        }
        if (l16 == 0) {
            z3[i] = al;
            r3[i] = ar + b3[0];
        }
    }
}

// ---------------------------------------------------------------------------
// Final (r10): 4 nodes/wave sigmoid + partial sums, with the MEAN fused via
// last-block-done atomic (threadfence release/acquire; counter zeroed by the
// per-launch hipMemsetAsync). Saves the separate mean launch gap.
// ---------------------------------------------------------------------------
__global__ __launch_bounds__(256) void final_kernel(
    const float* __restrict__ z3, const float* __restrict__ r3,
    const int* __restrict__ beg, const int* __restrict__ eend,
    const int* __restrict__ csr, const float* __restrict__ inv,
    float* __restrict__ out, float* __restrict__ partial,
    int* __restrict__ done) {
    __shared__ float red[4];
    __shared__ int lastFlag;
    const int wv   = (blockIdx.x * 256 + threadIdx.x) >> 6;  // global wave id
    const int lane = threadIdx.x & 63;
    const int sub  = lane >> 4;          // node sub-slot 0..3
    const int l16  = lane & 15;
    const int w    = threadIdx.x >> 6;
    const int i    = wv * 4 + sub;
    float s = 0.f;
    if (i < NN) {
        const int b0 = beg[i], e0 = eend[i];
        float a = 0.f;
        for (int e = b0 + l16; e < e0; e += 16) a += z3[csr[e]];
        a += __shfl_xor(a, 1, 64);
        a += __shfl_xor(a, 2, 64);
        a += __shfl_xor(a, 4, 64);
        a += __shfl_xor(a, 8, 64);
        const float pre = a * inv[i] + r3[i];
        const float sg  = 1.f / (1.f + __expf(-pre));
        if (l16 == 0) { out[i] = sg; s = sg; }
    }
    s += __shfl_xor(s, 16, 64);
    s += __shfl_xor(s, 32, 64);
    if (lane == 0) red[w] = s;
    __syncthreads();
    if (threadIdx.x == 0) {
        partial[blockIdx.x] = red[0] + red[1] + red[2] + red[3];
        __threadfence();                         // release partial store
        lastFlag = (atomicAdd(done, 1) == FB - 1);
    }
    __syncthreads();
    if (!lastFlag) return;

    // last block: sum all partials -> mean
    __threadfence();                             // acquire others' partials
    __shared__ float lds[256];
    float acc = 0.f;
    for (int j = threadIdx.x; j < FB; j += 256) acc += partial[j];
    lds[threadIdx.x] = acc;
    __syncthreads();
    for (int st = 128; st; st >>= 1) {
        if (threadIdx.x < st) lds[threadIdx.x] += lds[threadIdx.x + st];
        __syncthreads();
    }
    if (threadIdx.x == 0) out[NN] = lds[0] / (float)NN;
}

// ---------------------------------------------------------------------------
extern "C" void kernel_launch(void* const* d_in, const int* in_sizes, int n_in,
                              void* d_out, int out_size, void* d_ws, size_t ws_size,
                              hipStream_t stream) {
    const float* x    = (const float*)d_in[0];
    const float* diff = (const float*)d_in[1];
    const float* rec  = (const float*)d_in[2];
    const float* hid  = (const float*)d_in[3];
    const int* edge   = (const int*)d_in[4];
    const int* esrc = edge;        // row 0
    const int* edst = edge + EE;   // row 1
    const float* Wl0 = (const float*)d_in[5];
    const float* Wr0 = (const float*)d_in[6];
    const float* b0  = (const float*)d_in[7];
    const float* Wl1 = (const float*)d_in[8];
    const float* Wr1 = (const float*)d_in[9];
    const float* b1  = (const float*)d_in[10];
    const float* Wl2 = (const float*)d_in[11];
    const float* Wr2 = (const float*)d_in[12];
    const float* b2  = (const float*)d_in[13];
    const float* Wl3 = (const float*)d_in[14];
    const float* Wr3 = (const float*)d_in[15];
    const float* b3  = (const float*)d_in[16];
    float* out = (float*)d_out;

    // workspace carve-out (256B aligned) — total ~70 MB
    char* w = (char*)d_ws;
    auto alloc = [&](size_t bytes) -> void* {
        void* p = (void*)w;
        w += (bytes + 255) & ~(size_t)255;
        return p;
    };
    __hip_bfloat16* bufA = (__hip_bfloat16*)alloc((size_t)NN * HH * 2);  // 25.6 MB
    __hip_bfloat16* bufB = (__hip_bfloat16*)alloc((size_t)NN * HH * 2);  // 25.6 MB
    __hip_bfloat16* WT0  = (__hip_bfloat16*)alloc((size_t)256 * 256 * 2);
    __hip_bfloat16* WT1  = (__hip_bfloat16*)alloc((size_t)256 * 128 * 2);
    __hip_bfloat16* WT2  = (__hip_bfloat16*)alloc((size_t)256 * 128 * 2);
    int*   pairs   = (int*)alloc((size_t)NB * CAP * 4);                  // 8.0 MB
    int*   csr     = (int*)alloc((size_t)NB * CAP * 4);                  // 8.0 MB
    int*   bcur    = (int*)alloc((size_t)512 * 4);
    int*   beg     = (int*)alloc((size_t)NN * 4);
    int*   eend    = (int*)alloc((size_t)NN * 4);
    float* inv     = (float*)alloc((size_t)NN * 4);
    float* z3      = (float*)alloc((size_t)NN * 4);
    float* r3      = (float*)alloc((size_t)NN * 4);
    float* partial = (float*)alloc((size_t)25000 * 4);
    int*   done    = bcur + 500;    // inside the zeroed region, above NB

    // zero bucket cursors + done counter (graph-capture-safe async memset)
    hipMemsetAsync(bcur, 0, 512 * 4, stream);

    // Launch 1: edge scatter fused with weight prep
    prep_scatter_kernel<<<SB + PPB, 256, 0, stream>>>(
        Wl0, Wr0, Wl1, Wr1, Wl2, Wr2, WT0, WT1, WT2,
        esrc, edst, bcur, pairs);

    // Launch 2: finalize CSR (blocks 0..NB) fused with gemm L0 (z->A, r->B)
    fin_gemm0_kernel<<<NB + GB, 256, 0, stream>>>(
        x, diff, rec, hid, WT0, b0, bufA, bufB,
        bcur, pairs, csr, beg, eend, inv);

    // agg L0: h1 -> B (over r)
    aggregate_kernel<false><<<AB, 256, 0, stream>>>(bufA, bufB, beg, eend, csr, inv,
                                                    nullptr, nullptr, nullptr,
                                                    nullptr, nullptr);

    // L1: h in B; z in-place -> B, r -> A; agg: h2 -> A
    gemm_kernel<128><<<GB, 256, 0, stream>>>(bufB, WT1, b1, bufB, bufA);
    aggregate_kernel<false><<<AB, 256, 0, stream>>>(bufB, bufA, beg, eend, csr, inv,
                                                    nullptr, nullptr, nullptr,
                                                    nullptr, nullptr);

    // L2: h in A; z in-place -> A, r -> B; agg(LAST): fused proj3 -> z3, r3
    gemm_kernel<128><<<GB, 256, 0, stream>>>(bufA, WT2, b2, bufA, bufB);
    aggregate_kernel<true><<<AB, 256, 0, stream>>>(bufA, bufB, beg, eend, csr, inv,
                                                   Wl3, Wr3, b3, z3, r3);

    // final: sigmoid + partial sums + fused mean (last-block atomic)
    final_kernel<<<FB, 256, 0, stream>>>(z3, r3, beg, eend, csr, inv,
                                         out, partial, done);
}

// Round 11
// 453.995 us; speedup vs baseline: 1.2705x; 1.2705x over previous
//
#include <hip/hip_runtime.h>
#include <hip/hip_bf16.h>

// Problem constants (fixed by reference)
#define NN 100000
#define EE 1600000
#define HH 128
#define NB 391      // buckets = ceil(NN/256)
#define CAP 5120    // padded bucket capacity
#define GB 1563     // gemm tiles = ceil(NN/64)
#define SB 256      // scatter blocks
#define EPB (EE / SB)   // 6250 edges per scatter block (exact)
#define PPB 512     // prep blocks (131072 weight elems / 256)
#define FB 6250     // final blocks: 16 nodes/block (4 waves x 4 nodes)
#define AB 6250     // aggregate blocks: 16 nodes/block

typedef short bf16x8 __attribute__((ext_vector_type(8)));
typedef short bf16x4 __attribute__((ext_vector_type(4)));
typedef float f32x4  __attribute__((ext_vector_type(4)));

__device__ inline short f2bf(float v) {
    __hip_bfloat16 b = __float2bfloat16(v);
    return *reinterpret_cast<short*>(&b);
}
__device__ inline float bf2f(short s) {
    unsigned int u = ((unsigned int)(unsigned short)s) << 16;
    return *reinterpret_cast<float*>(&u);
}

// direct global->LDS staging (16B per lane, LDS dest = uniform base + lane*16)
typedef __attribute__((address_space(1))) void gvoid_t;
typedef __attribute__((address_space(3))) void svoid_t;
__device__ __forceinline__ void gload16(const void* g, void* l) {
    __builtin_amdgcn_global_load_lds((gvoid_t*)g, (svoid_t*)l, 16, 0, 0);
}

// Compiler-order fence (r2 lesson: asm waitcnt orders the HW, not the compiler)
__device__ __forceinline__ void ld_fence() { asm volatile("" ::: "memory"); }

// counted-vmcnt barrier: wait own outstanding vmem down to N, then raw s_barrier.
template <int N>
__device__ __forceinline__ void wait_vm_bar() {
    if constexpr (N == 0)
        asm volatile("s_waitcnt vmcnt(0)\n\ts_barrier" ::: "memory");
    else if constexpr (N == 4)
        asm volatile("s_waitcnt vmcnt(4)\n\ts_barrier" ::: "memory");
    else if constexpr (N == 12)
        asm volatile("s_waitcnt vmcnt(12)\n\ts_barrier" ::: "memory");
    else if constexpr (N == 16)
        asm volatile("s_waitcnt vmcnt(16)\n\ts_barrier" ::: "memory");
    else if constexpr (N == 18)
        asm volatile("s_waitcnt vmcnt(18)\n\ts_barrier" ::: "memory");
    else
        static_assert(N == 0 || N == 4 || N == 12 || N == 16 || N == 18, "bad N");
}
__device__ __forceinline__ void barrier_only() {
    asm volatile("s_barrier" ::: "memory");
}

// ---------------------------------------------------------------------------
// Launch 1: edge scatter (blocks [0,SB)) FUSED with weight prep
// (blocks [SB, SB+PPB)). bcur zeroed by hipMemsetAsync.
// Scatter: SB x 6250 edges, 16-deep register-blocked loads both passes.
// ---------------------------------------------------------------------------
__global__ __launch_bounds__(256) void prep_scatter_kernel(
    const float* __restrict__ Wl0, const float* __restrict__ Wr0,
    const float* __restrict__ Wl1, const float* __restrict__ Wr1,
    const float* __restrict__ Wl2, const float* __restrict__ Wr2,
    __hip_bfloat16* __restrict__ WT0, __hip_bfloat16* __restrict__ WT1,
    __hip_bfloat16* __restrict__ WT2,
    const int* __restrict__ srcv, const int* __restrict__ dstv,
    int* __restrict__ bcur, int* __restrict__ pairs) {
    __shared__ int hist[NB];
    __shared__ int base[NB];
    const int t = threadIdx.x;

    if (blockIdx.x >= SB) {                      // weight prep
        int id = (blockIdx.x - SB) * 256 + t;    // 0 .. 131071
        if (id < 65536) {                        // layer 0: K=256
            int k = id & 255, n = id >> 8;
            float v = (n < 128) ? Wl0[(size_t)k * 128 + n]
                                : Wr0[(size_t)k * 128 + (n - 128)];
            WT0[(size_t)n * 256 + k] = __float2bfloat16(v);
        } else {
            id -= 65536;
            int layer = id >> 15;                // 0 -> L1, 1 -> L2
            int u = id & 32767;
            int k = u & 127, n = u >> 7;
            const float* Wl = layer ? Wl2 : Wl1;
            const float* Wr = layer ? Wr2 : Wr1;
            __hip_bfloat16* WT = layer ? WT2 : WT1;
            float v = (n < 128) ? Wl[(size_t)k * 128 + n]
                                : Wr[(size_t)k * 128 + (n - 128)];
            WT[(size_t)n * 128 + k] = __float2bfloat16(v);
        }
        return;
    }

    for (int j = t; j < NB; j += 256) hist[j] = 0;
    __syncthreads();

    const int e0    = blockIdx.x * EPB;
    const int eend_ = e0 + EPB;

    for (int be = e0; be < eend_; be += 4096) {
        int d[16];
#pragma unroll
        for (int u = 0; u < 16; ++u) {
            const int e = be + u * 256 + t;
            d[u] = (e < eend_) ? dstv[e] : -1;
        }
#pragma unroll
        for (int u = 0; u < 16; ++u)
            if (d[u] >= 0) atomicAdd(&hist[d[u] >> 8], 1);
    }
    __syncthreads();

    for (int j = t; j < NB; j += 256)
        base[j] = hist[j] ? atomicAdd(&bcur[j], hist[j]) : 0;
    __syncthreads();
    for (int j = t; j < NB; j += 256) hist[j] = base[j];   // reuse as cursor
    __syncthreads();

    for (int be = e0; be < eend_; be += 4096) {
        int s[16], d[16];
#pragma unroll
        for (int u = 0; u < 16; ++u) {
            const int e = be + u * 256 + t;
            if (e < eend_) { s[u] = srcv[e]; d[u] = dstv[e]; }
            else d[u] = -1;
        }
#pragma unroll
        for (int u = 0; u < 16; ++u)
            if (d[u] >= 0) {
                const int b   = d[u] >> 8;
                const int pos = atomicAdd(&hist[b], 1);
                if (pos < CAP) pairs[b * CAP + pos] = (s[u] << 8) | (d[u] & 255);
            }
    }
}

// ---------------------------------------------------------------------------
// MFMA GEMM body (r10): [z|r] = h @ [Wl|Wr], 64-row tile, 4 waves.
// L0 DBUF (2x16KB stage, epilogue aliased) -> LDS 33.8KB -> 4 blocks/CU.
// Fenced issue order + counted vmcnt waits. VGPR ~92 (2-deep wreg).
// ---------------------------------------------------------------------------
#define EW 264    // epilogue LDS row stride in halves (528 B, 16B-aligned)
template <int K, bool FIRST>
__device__ __forceinline__ void gemm_body(
    short* __restrict__ lsh, int bid,
    const __hip_bfloat16* hin,
    const float* __restrict__ x0, const float* __restrict__ x1,
    const float* __restrict__ x2, const float* __restrict__ x3,
    const __hip_bfloat16* __restrict__ wt, const float* __restrict__ bias,
    __hip_bfloat16* zout, __hip_bfloat16* __restrict__ rout) {
    const int t    = threadIdx.x;
    const int w    = t >> 6;
    const int lane = t & 63;
    const int quad = lane >> 4;
    const int l16  = lane & 15;
    const int n0   = bid * 64;

    constexpr int BUFB = FIRST ? 16384 : 8192;   // LDS bytes per stage buffer
    char* const lc = (char*)lsh;

    const __hip_bfloat16* afeat[4];
#pragma unroll
    for (int ft = 0; ft < 4; ++ft)
        afeat[ft] = wt + (size_t)(w * 64 + ft * 16 + l16) * K + quad * 8;

    f32x4 acc[4][4];
#pragma unroll
    for (int ft = 0; ft < 4; ++ft)
#pragma unroll
        for (int nt = 0; nt < 4; ++nt)
            acc[ft][nt] = (f32x4){0.f, 0.f, 0.f, 0.f};

    bf16x8 wreg[2][8];   // [parity][kcl*4+ft]

    auto loadW = [&](int p, int pb) {
#pragma unroll
        for (int kcl = 0; kcl < 2; ++kcl)
#pragma unroll
            for (int ft = 0; ft < 4; ++ft)
                wreg[pb][kcl * 4 + ft] =
                    *(const bf16x8*)(afeat[ft] + (p * 2 + kcl) * 32);
    };

    auto stage = [&](int p, int bb) {
        char* lb = lc + bb * BUFB;
        if constexpr (FIRST) {
            const float* sp = (p == 0) ? x0 : (p == 1) ? x1 : (p == 2) ? x2 : x3;
#pragma unroll
            for (int i = 0; i < 4; ++i) {
                const int j   = w * 4 + i;           // 1KB chunk = 4 rows
                const int row = j * 4 + (lane >> 4);
                int rg = n0 + row; if (rg > NN - 1) rg = NN - 1;
                const int colb = ((lane & 15) * 16) ^ ((row & 15) << 4);
                gload16((const char*)sp + (size_t)rg * 256 + colb, lb + j * 1024);
            }
        } else {
#pragma unroll
            for (int i = 0; i < 2; ++i) {
                const int j   = w * 2 + i;           // 1KB chunk = 8 rows
                const int row = j * 8 + (lane >> 3);
                int rg = n0 + row; if (rg > NN - 1) rg = NN - 1;
                const int colb = ((lane & 7) * 16) ^ ((row & 7) << 4);
                gload16((const char*)hin + (size_t)rg * 256 + p * 128 + colb,
                        lb + j * 1024);
            }
        }
    };

    auto compute = [&](int s, int bb, int pb) {
        const char* lb = lc + bb * BUFB;
#pragma unroll
        for (int kcl = 0; kcl < 2; ++kcl) {
#pragma unroll
            for (int nt = 0; nt < 4; ++nt) {
                const int row = nt * 16 + l16;
                bf16x8 b;
                if constexpr (FIRST) {
                    const int sw = (row & 15) << 4;
                    const int B0 = kcl * 128 + quad * 32;
                    const char* rb = lb + row * 256;
                    const f32x4 lo = *(const f32x4*)(rb + ((B0) ^ sw));
                    const f32x4 hi = *(const f32x4*)(rb + ((B0 + 16) ^ sw));
                    b[0] = f2bf(lo[0]); b[1] = f2bf(lo[1]);
                    b[2] = f2bf(lo[2]); b[3] = f2bf(lo[3]);
                    b[4] = f2bf(hi[0]); b[5] = f2bf(hi[1]);
                    b[6] = f2bf(hi[2]); b[7] = f2bf(hi[3]);
                } else {
                    const int sw = (row & 7) << 4;
                    const int B0 = kcl * 64 + quad * 16;
                    b = *(const bf16x8*)(lb + row * 128 + (B0 ^ sw));
                }
#pragma unroll
                for (int ft = 0; ft < 4; ++ft)
                    acc[ft][nt] = __builtin_amdgcn_mfma_f32_16x16x32_bf16(
                        wreg[pb][kcl * 4 + ft], b, acc[ft][nt], 0, 0, 0);
            }
        }
    };

    if constexpr (FIRST) {                   // NS=4, 2 LDS buffers (dbuf)
        loadW(0, 0); ld_fence();
        loadW(1, 1); ld_fence();
        stage(0, 0); ld_fence();
        stage(1, 1); ld_fence();
        // queue: W0(8) W1(8) S0(4) S1(4) = 24
        wait_vm_bar<4>();                      // retire W0,W1,S0; S1 in flight
        compute(0, 0, 0); barrier_only();
        stage(2, 0); ld_fence(); loadW(2, 0); ld_fence();   // out: S1+S2+W2=16
        wait_vm_bar<12>();                     // retire S1; S2,W2 in flight
        compute(1, 1, 1); barrier_only();
        stage(3, 1); ld_fence(); loadW(3, 1); ld_fence();   // out: S2+W2+S3+W3=24
        wait_vm_bar<12>();                     // retire S2,W2; S3,W3 in flight
        compute(2, 0, 0); barrier_only();
        wait_vm_bar<0>();                      // retire S3,W3
        compute(3, 1, 1); barrier_only();
    } else {                                  // NS=2, 2 LDS buffers
        stage(0, 0); ld_fence();
        stage(1, 1); ld_fence();
        loadW(0, 0); loadW(1, 1);
        wait_vm_bar<18>(); compute(0, 0, 0); barrier_only();
        wait_vm_bar<16>(); compute(1, 1, 1); barrier_only();
    }

    // merged epilogue: all 4 waves transpose into [64][256] (z | r+bias),
    // one sync, one cooperative store pass. Aliases the stage buffers.
#pragma unroll
    for (int ft = 0; ft < 4; ++ft) {
        const int fb = ft * 16 + quad * 4;
        float4 bv = make_float4(0.f, 0.f, 0.f, 0.f);
        if (w >= 2) bv = *(const float4*)&bias[(w - 2) * 64 + fb];
        const int cbase = (w & 1) * 64 + ((w >= 2) ? 128 : 0);
#pragma unroll
        for (int nt = 0; nt < 4; ++nt) {
            const f32x4 a = acc[ft][nt];
            bf16x4 p;
            p[0] = f2bf(a[0] + bv.x); p[1] = f2bf(a[1] + bv.y);
            p[2] = f2bf(a[2] + bv.z); p[3] = f2bf(a[3] + bv.w);
            *(bf16x4*)&lsh[(nt * 16 + l16) * EW + cbase + fb] = p;
        }
    }
    __syncthreads();
#pragma unroll
    for (int u = 0; u < 8; ++u) {            // 64 rows x 32 bf16x8-chunks
        const int id  = u * 256 + t;
        const int row = id >> 5, ch = (id & 31) * 8;
        const int nd  = n0 + row;
        if (nd < NN) {
            const bf16x8 v = *(const bf16x8*)&lsh[row * EW + ch];
            if (ch < 128) *(bf16x8*)&zout[(size_t)nd * HH + ch] = v;
            else          *(bf16x8*)&rout[(size_t)nd * HH + (ch - 128)] = v;
        }
    }
}

// hidden gemm (layers 1,2): LDS = max(2x8KB dbuf, 64x264x2 epilogue) = 33.8KB
template <int K>
__global__ __launch_bounds__(256) void gemm_kernel(
    const __hip_bfloat16* hin,
    const __hip_bfloat16* __restrict__ wt, const float* __restrict__ bias,
    __hip_bfloat16* zout, __hip_bfloat16* __restrict__ rout) {
    __shared__ short lsh[16896];
    gemm_body<K, false>(lsh, blockIdx.x, hin, nullptr, nullptr, nullptr, nullptr,
                        wt, bias, zout, rout);
}

// ---------------------------------------------------------------------------
// Launch 2: FINALIZE (blocks [0,NB)) fused with GEMM L0 (blocks [NB, NB+GB)).
// ---------------------------------------------------------------------------
__global__ __launch_bounds__(256) void fin_gemm0_kernel(
    const float* __restrict__ x0, const float* __restrict__ x1,
    const float* __restrict__ x2, const float* __restrict__ x3,
    const __hip_bfloat16* __restrict__ wt, const float* __restrict__ bias,
    __hip_bfloat16* __restrict__ zout, __hip_bfloat16* __restrict__ rout,
    const int* __restrict__ bcur, const int* __restrict__ pairs,
    int* __restrict__ csr, int* __restrict__ beg, int* __restrict__ eend,
    float* __restrict__ inv) {
    __shared__ short lsh[16896];            // gemm: 2x16KB dbuf; finalize 3KB
    const int t = threadIdx.x;

    if (blockIdx.x >= NB) {
        gemm_body<256, true>(lsh, blockIdx.x - NB, nullptr, x0, x1, x2, x3,
                             wt, bias, zout, rout);
        return;
    }

    int* cnt = (int*)lsh;
    int* scn = cnt + 256;
    int* cur = scn + 256;
    const int b = blockIdx.x;
    int m = bcur[b];
    if (m > CAP) m = CAP;

    cnt[t] = 0;
    __syncthreads();
    for (int e = t; e < m; e += 256)
        atomicAdd(&cnt[pairs[b * CAP + e] & 255], 1);
    __syncthreads();

    const int v = cnt[t];
    scn[t] = v;
    __syncthreads();
    for (int st = 1; st < 256; st <<= 1) {
        int tv = (t >= st) ? scn[t - st] : 0;
        __syncthreads();
        scn[t] += tv;
        __syncthreads();
    }
    const int myStart = scn[t] - v;          // exclusive scan
    cur[t] = myStart;
    __syncthreads();

    for (int e = t; e < m; e += 256) {
        const int pk  = pairs[b * CAP + e];
        const int pos = atomicAdd(&cur[pk & 255], 1);
        csr[b * CAP + pos] = pk >> 8;
    }

    const int node = b * 256 + t;
    if (node < NN) {
        beg[node]  = b * CAP + myStart;
        eend[node] = b * CAP + myStart + v;
        inv[node]  = 1.0f / fmaxf((float)v, 1.0f);
    }
}

// ---------------------------------------------------------------------------
// Aggregation + combine (r10): 4 nodes/wave, 16-lane groups, lane-local
// features, 8-deep edge unroll. LAST: fused proj3 + 4-shfl group reduce.
// ---------------------------------------------------------------------------
template <bool LAST>
__global__ __launch_bounds__(256) void aggregate_kernel(
    const __hip_bfloat16* __restrict__ z, __hip_bfloat16* __restrict__ rio,
    const int* __restrict__ beg, const int* __restrict__ eend,
    const int* __restrict__ csr, const float* __restrict__ inv,
    const float* __restrict__ Wl3, const float* __restrict__ Wr3,
    const float* __restrict__ b3, float* __restrict__ z3,
    float* __restrict__ r3) {
    const int lane = threadIdx.x & 63;
    const int g    = lane >> 4;          // node sub-slot 0..3
    const int l16  = lane & 15;          // feature chunk within the row
    const int i    = ((blockIdx.x * 256 + threadIdx.x) >> 6) * 4 + g;
    if (i >= NN) return;
    const int b0 = beg[i], e0 = eend[i];
    const float iv = inv[i];
    const int  f   = l16 * 8;

    const bf16x8 rv8 = *(const bf16x8*)&rio[(size_t)i * HH + f];

    float acc[8];
#pragma unroll
    for (int j = 0; j < 8; ++j) acc[j] = 0.f;

    const size_t zoff = (size_t)f;
    int e = b0;
    for (; e + 7 < e0; e += 8) {
        int s[8];
#pragma unroll
        for (int u = 0; u < 8; ++u) s[u] = csr[e + u];
        bf16x8 zv[8];
#pragma unroll
        for (int u = 0; u < 8; ++u)
            zv[u] = *(const bf16x8*)&z[(size_t)s[u] * HH + zoff];
#pragma unroll
        for (int j = 0; j < 8; ++j) {
            float a0 = bf2f(zv[0][j]) + bf2f(zv[1][j]);
            float a1 = bf2f(zv[2][j]) + bf2f(zv[3][j]);
            float a2 = bf2f(zv[4][j]) + bf2f(zv[5][j]);
            float a3 = bf2f(zv[6][j]) + bf2f(zv[7][j]);
            acc[j] += (a0 + a1) + (a2 + a3);
        }
    }
    if (e + 3 < e0) {                    // unmasked 4-batch
        const int s0 = csr[e], s1 = csr[e + 1], s2 = csr[e + 2], s3 = csr[e + 3];
        const bf16x8 z0 = *(const bf16x8*)&z[(size_t)s0 * HH + zoff];
        const bf16x8 z1 = *(const bf16x8*)&z[(size_t)s1 * HH + zoff];
        const bf16x8 z2 = *(const bf16x8*)&z[(size_t)s2 * HH + zoff];
        const bf16x8 z3v = *(const bf16x8*)&z[(size_t)s3 * HH + zoff];
#pragma unroll
        for (int j = 0; j < 8; ++j)
            acc[j] += (bf2f(z0[j]) + bf2f(z1[j])) + (bf2f(z2[j]) + bf2f(z3v[j]));
        e += 4;
    }
    if (e < e0) {                        // masked tail (1..3 edges)
        const int s0 = csr[e];
        const int s1 = (e + 1 < e0) ? csr[e + 1] : s0;
        const int s2 = (e + 2 < e0) ? csr[e + 2] : s0;
        const float m1 = (e + 1 < e0) ? 1.f : 0.f;
        const float m2 = (e + 2 < e0) ? 1.f : 0.f;
        const bf16x8 z0 = *(const bf16x8*)&z[(size_t)s0 * HH + zoff];
        const bf16x8 z1 = *(const bf16x8*)&z[(size_t)s1 * HH + zoff];
        const bf16x8 z2 = *(const bf16x8*)&z[(size_t)s2 * HH + zoff];
#pragma unroll
        for (int j = 0; j < 8; ++j) {
            acc[j] += bf2f(z0[j]);
            acc[j] = fmaf(m1, bf2f(z1[j]), acc[j]);
            acc[j] = fmaf(m2, bf2f(z2[j]), acc[j]);
        }
    }

    float ox[8];
    const __hip_bfloat162* rp = (const __hip_bfloat162*)&rv8;
#pragma unroll
    for (int j = 0; j < 4; ++j) {
        ox[2 * j]     = fmaxf(acc[2 * j]     * iv + __bfloat162float(rp[j].x), 0.f);
        ox[2 * j + 1] = fmaxf(acc[2 * j + 1] * iv + __bfloat162float(rp[j].y), 0.f);
    }

    if (!LAST) {
        bf16x8 o;
#pragma unroll
        for (int j = 0; j < 8; ++j) o[j] = f2bf(ox[j]);
        *(bf16x8*)&rio[(size_t)i * HH + f] = o;
    } else {
        const float4 wl0 = *(const float4*)&Wl3[f];
        const float4 wl1 = *(const float4*)&Wl3[f + 4];
        const float4 wr0 = *(const float4*)&Wr3[f];
        const float4 wr1 = *(const float4*)&Wr3[f + 4];
        float al = ox[0] * wl0.x + ox[1] * wl0.y + ox[2] * wl0.z + ox[3] * wl0.w
                 + ox[4] * wl1.x + ox[5] * wl1.y + ox[6] * wl1.z + ox[7] * wl1.w;
        float ar = ox[0] * wr0.x + ox[1] * wr0.y + ox[2] * wr0.z + ox[3] * wr0.w
                 + ox[4] * wr1.x + ox[5] * wr1.y + ox[6] * wr1.z + ox[7] * wr1.w;
#pragma unroll
        for (int m = 8; m; m >>= 1) {     // reduce within the 16-lane group
            al += __shfl_xor(al, m, 64);
            ar += __shfl_xor(ar, m, 64);
        }
        if (l16 == 0) {
            z3[i] = al;
            r3[i] = ar + b3[0];
        }
    }
}

// ---------------------------------------------------------------------------
// Final (r11 = r9): 4 nodes/wave sigmoid + per-block partial stores. The
// r10 fused-mean (threadfence + last-block) cost 145us — device-scope
// __threadfence on gfx950 = L2 writeback across non-coherent XCD L2s,
// paid 6250x. Kernel boundary pays that visibility cost ONCE.
// ---------------------------------------------------------------------------
__global__ __launch_bounds__(256) void final_kernel(
    const float* __restrict__ z3, const float* __restrict__ r3,
    const int* __restrict__ beg, const int* __restrict__ eend,
    const int* __restrict__ csr, const float* __restrict__ inv,
    float* __restrict__ out, float* __restrict__ partial) {
    __shared__ float red[4];
    const int wv   = (blockIdx.x * 256 + threadIdx.x) >> 6;  // global wave id
    const int lane = threadIdx.x & 63;
    const int sub  = lane >> 4;          // node sub-slot 0..3
    const int l16  = lane & 15;
    const int w    = threadIdx.x >> 6;
    const int i    = wv * 4 + sub;
    float s = 0.f;
    if (i < NN) {
        const int b0 = beg[i], e0 = eend[i];
        float a = 0.f;
        for (int e = b0 + l16; e < e0; e += 16) a += z3[csr[e]];
        a += __shfl_xor(a, 1, 64);
        a += __shfl_xor(a, 2, 64);
        a += __shfl_xor(a, 4, 64);
        a += __shfl_xor(a, 8, 64);
        const float pre = a * inv[i] + r3[i];
        const float sg  = 1.f / (1.f + __expf(-pre));
        if (l16 == 0) { out[i] = sg; s = sg; }
    }
    s += __shfl_xor(s, 16, 64);
    s += __shfl_xor(s, 32, 64);
    if (lane == 0) red[w] = s;
    __syncthreads();
    if (threadIdx.x == 0)
        partial[blockIdx.x] = red[0] + red[1] + red[2] + red[3];
}

__global__ __launch_bounds__(256) void mean_kernel(const float* __restrict__ partial,
                                                   int nb, float* __restrict__ out) {
    __shared__ float lds[256];
    float s = 0.f;
    for (int i = threadIdx.x; i < nb; i += 256) s += partial[i];
    lds[threadIdx.x] = s;
    __syncthreads();
    for (int st = 128; st; st >>= 1) {
        if (threadIdx.x < st) lds[threadIdx.x] += lds[threadIdx.x + st];
        __syncthreads();
    }
    if (threadIdx.x == 0) out[NN] = lds[0] / (float)NN;
}

// ---------------------------------------------------------------------------
extern "C" void kernel_launch(void* const* d_in, const int* in_sizes, int n_in,
                              void* d_out, int out_size, void* d_ws, size_t ws_size,
                              hipStream_t stream) {
    const float* x    = (const float*)d_in[0];
    const float* diff = (const float*)d_in[1];
    const float* rec  = (const float*)d_in[2];
    const float* hid  = (const float*)d_in[3];
    const int* edge   = (const int*)d_in[4];
    const int* esrc = edge;        // row 0
    const int* edst = edge + EE;   // row 1
    const float* Wl0 = (const float*)d_in[5];
    const float* Wr0 = (const float*)d_in[6];
    const float* b0  = (const float*)d_in[7];
    const float* Wl1 = (const float*)d_in[8];
    const float* Wr1 = (const float*)d_in[9];
    const float* b1  = (const float*)d_in[10];
    const float* Wl2 = (const float*)d_in[11];
    const float* Wr2 = (const float*)d_in[12];
    const float* b2  = (const float*)d_in[13];
    const float* Wl3 = (const float*)d_in[14];
    const float* Wr3 = (const float*)d_in[15];
    const float* b3  = (const float*)d_in[16];
    float* out = (float*)d_out;

    // workspace carve-out (256B aligned) — total ~70 MB
    char* w = (char*)d_ws;
    auto alloc = [&](size_t bytes) -> void* {
        void* p = (void*)w;
        w += (bytes + 255) & ~(size_t)255;
        return p;
    };
    __hip_bfloat16* bufA = (__hip_bfloat16*)alloc((size_t)NN * HH * 2);  // 25.6 MB
    __hip_bfloat16* bufB = (__hip_bfloat16*)alloc((size_t)NN * HH * 2);  // 25.6 MB
    __hip_bfloat16* WT0  = (__hip_bfloat16*)alloc((size_t)256 * 256 * 2);
    __hip_bfloat16* WT1  = (__hip_bfloat16*)alloc((size_t)256 * 128 * 2);
    __hip_bfloat16* WT2  = (__hip_bfloat16*)alloc((size_t)256 * 128 * 2);
    int*   pairs   = (int*)alloc((size_t)NB * CAP * 4);                  // 8.0 MB
    int*   csr     = (int*)alloc((size_t)NB * CAP * 4);                  // 8.0 MB
    int*   bcur    = (int*)alloc((size_t)512 * 4);
    int*   beg     = (int*)alloc((size_t)NN * 4);
    int*   eend    = (int*)alloc((size_t)NN * 4);
    float* inv     = (float*)alloc((size_t)NN * 4);
    float* z3      = (float*)alloc((size_t)NN * 4);
    float* r3      = (float*)alloc((size_t)NN * 4);
    float* partial = (float*)alloc((size_t)25000 * 4);

    // zero bucket cursors (graph-capture-safe async memset)
    hipMemsetAsync(bcur, 0, 512 * 4, stream);

    // Launch 1: edge scatter fused with weight prep
    prep_scatter_kernel<<<SB + PPB, 256, 0, stream>>>(
        Wl0, Wr0, Wl1, Wr1, Wl2, Wr2, WT0, WT1, WT2,
        esrc, edst, bcur, pairs);

    // Launch 2: finalize CSR (blocks 0..NB) fused with gemm L0 (z->A, r->B)
    fin_gemm0_kernel<<<NB + GB, 256, 0, stream>>>(
        x, diff, rec, hid, WT0, b0, bufA, bufB,
        bcur, pairs, csr, beg, eend, inv);

    // agg L0: h1 -> B (over r)
    aggregate_kernel<false><<<AB, 256, 0, stream>>>(bufA, bufB, beg, eend, csr, inv,
                                                    nullptr, nullptr, nullptr,
                                                    nullptr, nullptr);

    // L1: h in B; z in-place -> B, r -> A; agg: h2 -> A
    gemm_kernel<128><<<GB, 256, 0, stream>>>(bufB, WT1, b1, bufB, bufA);
    aggregate_kernel<false><<<AB, 256, 0, stream>>>(bufB, bufA, beg, eend, csr, inv,
                                                    nullptr, nullptr, nullptr,
                                                    nullptr, nullptr);

    // L2: h in A; z in-place -> A, r -> B; agg(LAST): fused proj3 -> z3, r3
    gemm_kernel<128><<<GB, 256, 0, stream>>>(bufA, WT2, b2, bufA, bufB);
    aggregate_kernel<true><<<AB, 256, 0, stream>>>(bufA, bufB, beg, eend, csr, inv,
                                                   Wl3, Wr3, b3, z3, r3);

    // final: sigmoid + partial sums; then mean (separate tiny launch)
    final_kernel<<<FB, 256, 0, stream>>>(z3, r3, beg, eend, csr, inv, out, partial);
    mean_kernel<<<1, 256, 0, stream>>>(partial, FB, out);
}